// Round 14
// baseline (118.760 us; speedup 1.0000x reference)
//
#include <hip/hip_runtime.h>
#include <hip/hip_bf16.h>
#include <math.h>

#define B_N 8
#define S_N 2048
#define C_N 384
#define D_N 64
#define NCHUNK 16         // i-chunks for col_part (128 rows each)
#define NEG_BIG (-1e30f)

typedef __bf16 bf16x8 __attribute__((ext_vector_type(8)));
typedef float f32x4 __attribute__((ext_vector_type(4)));

static __device__ __forceinline__ bf16x8 ldfrag(const __bf16* p) {
  return *reinterpret_cast<const bf16x8*>(p);
}

// ---------------------------------------------------------------------------
// Kernel 0: weight prep. Wt[m][d][c] = (bf16) W_m[c][d].
// ---------------------------------------------------------------------------
__global__ __launch_bounds__(256) void w_prep(
    const float* __restrict__ Wq, const float* __restrict__ Wk,
    const float* __restrict__ Wv, __bf16* __restrict__ Wt) {
  const int idx = blockIdx.x * 256 + threadIdx.x;   // [0, 3*64*384)
  const int m = idx / (64 * C_N);
  const int r = idx % (64 * C_N);
  const int d = r / C_N;
  const int c = r % C_N;
  const float* W = (m == 0) ? Wq : (m == 1) ? Wk : Wv;
  Wt[idx] = (__bf16)W[c * 64 + d];
}

// ---------------------------------------------------------------------------
// Kernel 1: QKV projection via MFMA (unchanged).
// ---------------------------------------------------------------------------
__global__ __launch_bounds__(384) void qkv_mfma(
    const float* __restrict__ x, const __bf16* __restrict__ Wt,
    __bf16* __restrict__ Q, __bf16* __restrict__ K, __bf16* __restrict__ Vt) {
  const int t = threadIdx.x;
  const int w = t >> 6, lane = t & 63, lr = lane & 15, lg = lane >> 4;
  const int mat = w >> 1, rh = w & 1;
  const int row0 = blockIdx.x * 32;                 // flat row in [0, B*S)
  const int ri = row0 + rh * 16 + lr;

  __shared__ __bf16 vtile[32][66];                  // V block, padded

  const float scl = (mat == 0) ? 0.125f : 1.0f;
  const float* xr = x + (size_t)ri * C_N;
  const __bf16* Wm = Wt + (size_t)mat * 64 * C_N;

  f32x4 acc[4];
#pragma unroll
  for (int nt = 0; nt < 4; ++nt) acc[nt] = {0.f, 0.f, 0.f, 0.f};

#pragma unroll 4
  for (int kk = 0; kk < C_N / 32; ++kk) {
    const float4 xa = *reinterpret_cast<const float4*>(xr + kk * 32 + lg * 8);
    const float4 xb = *reinterpret_cast<const float4*>(xr + kk * 32 + lg * 8 + 4);
    bf16x8 a;
    a[0] = (__bf16)(xa.x * scl); a[1] = (__bf16)(xa.y * scl);
    a[2] = (__bf16)(xa.z * scl); a[3] = (__bf16)(xa.w * scl);
    a[4] = (__bf16)(xb.x * scl); a[5] = (__bf16)(xb.y * scl);
    a[6] = (__bf16)(xb.z * scl); a[7] = (__bf16)(xb.w * scl);
#pragma unroll
    for (int nt = 0; nt < 4; ++nt) {
      const bf16x8 bw = ldfrag(Wm + (size_t)(nt * 16 + lr) * C_N + kk * 32 + lg * 8);
      acc[nt] = __builtin_amdgcn_mfma_f32_16x16x32_bf16(a, bw, acc[nt], 0, 0, 0);
    }
  }

  if (mat < 2) {
    __bf16* outp = (mat == 0) ? Q : K;
#pragma unroll
    for (int nt = 0; nt < 4; ++nt)
#pragma unroll
      for (int r = 0; r < 4; ++r)
        outp[(size_t)(row0 + rh * 16 + lg * 4 + r) * 64 + nt * 16 + lr] =
            (__bf16)acc[nt][r];
  } else {
#pragma unroll
    for (int nt = 0; nt < 4; ++nt)
#pragma unroll
      for (int r = 0; r < 4; ++r)
        vtile[rh * 16 + lg * 4 + r][nt * 16 + lr] = (__bf16)acc[nt][r];
  }
  __syncthreads();

  const int b = row0 >> 11, s0 = row0 & (S_N - 1);
  for (int idx = t; idx < 64 * 32; idx += 384) {
    const int d = idx >> 5, s2 = idx & 31;
    Vt[((size_t)b * D_N + d) * S_N + s0 + s2] = vtile[s2][d];
  }
}

// ---------------------------------------------------------------------------
// Kernel 2a: partial column denominators (m == 0). Unchanged from R12.
// ---------------------------------------------------------------------------
__global__ __launch_bounds__(256) void col_part(
    const __bf16* __restrict__ Q, const __bf16* __restrict__ K,
    float* __restrict__ zP) {
  const int wg = blockIdx.x;                       // 32*16*8 = 4096
  const int b  = wg & 7;
  const int jb = (wg >> 3) & 31;
  const int ic = wg >> 8;                          // 0..15
  const int j0 = jb * 64;
  const int t = threadIdx.x;
  const int iStart = max(j0, ic * (S_N / NCHUNK));
  const int iEnd = min(S_N, (ic + 1) * (S_N / NCHUNK));
  const size_t pbase = ((size_t)(b * 32 + jb) * NCHUNK + ic) * 4 * 64;

  if (iStart >= iEnd) {            // neutral partials (256 slots == 256 threads)
    zP[pbase + t] = 0.f;
    return;
  }

  const int w = t >> 6, lane = t & 63, lr = lane & 15, lg = lane >> 4;
  const __bf16* Qb = Q + (size_t)b * S_N * 64;
  const __bf16* Kb = K + (size_t)b * S_N * 64;

  bf16x8 bk[4][2];
#pragma unroll
  for (int jt = 0; jt < 4; ++jt) {
    bk[jt][0] = ldfrag(Kb + (size_t)(j0 + jt * 16 + lr) * 64 + lg * 8);
    bk[jt][1] = ldfrag(Kb + (size_t)(j0 + jt * 16 + lr) * 64 + 32 + lg * 8);
  }

  float z4[4];
#pragma unroll
  for (int jt = 0; jt < 4; ++jt) z4[jt] = 0.f;

  bf16x8 aq0c = ldfrag(Qb + (size_t)(iStart + w * 16 + lr) * 64 + lg * 8);
  bf16x8 aq1c = ldfrag(Qb + (size_t)(iStart + w * 16 + lr) * 64 + 32 + lg * 8);

  for (int i0 = iStart; i0 < iEnd; i0 += 64) {
    const int riN = ((i0 + 64 < iEnd) ? i0 + 64 : i0) + w * 16 + lr;
    const bf16x8 aq0n = ldfrag(Qb + (size_t)riN * 64 + lg * 8);
    const bf16x8 aq1n = ldfrag(Qb + (size_t)riN * 64 + 32 + lg * 8);

    const int ibase = i0 + w * 16 + lg * 4;       // D-row base for this lane
    const bool diag = (i0 == j0);
#pragma unroll
    for (int jt = 0; jt < 4; ++jt) {
      f32x4 s = {0.f, 0.f, 0.f, 0.f};
      s = __builtin_amdgcn_mfma_f32_16x16x32_bf16(aq0c, bk[jt][0], s, 0, 0, 0);
      s = __builtin_amdgcn_mfma_f32_16x16x32_bf16(aq1c, bk[jt][1], s, 0, 0, 0);
      const int jg = j0 + jt * 16 + lr;           // D col = lane&15
      if (diag) {
#pragma unroll
        for (int r = 0; r < 4; ++r)
          if (ibase + r < jg) s[r] = NEG_BIG;     // expf(-1e30) == 0
      }
      float es = __expf(s[0]) + __expf(s[1]) + __expf(s[2]) + __expf(s[3]);
      es += __shfl_xor(es, 16);
      es += __shfl_xor(es, 32);
      z4[jt] += es;
    }
    aq0c = aq0n;
    aq1c = aq1n;
  }

  if (lg == 0) {                                  // one copy per column
#pragma unroll
    for (int jt = 0; jt < 4; ++jt)
      zP[pbase + w * 64 + jt * 16 + lr] = z4[jt];
  }
}

// ---------------------------------------------------------------------------
// Kernel 2b: sum the NCHUNK*4 partials per column -> 1/Z.
// ---------------------------------------------------------------------------
__global__ __launch_bounds__(256) void col_reduce(
    const float* __restrict__ zP, float* __restrict__ rZ) {
  const int idx = blockIdx.x * 256 + threadIdx.x;  // b*S + j
  const int b = idx >> 11;
  const int j = idx & (S_N - 1);
  const int jb = j >> 6, jr = j & 63;
  const size_t base = (size_t)(b * 32 + jb) * NCHUNK * 4 * 64 + jr;

  float z = 0.f;
#pragma unroll 8
  for (int p = 0; p < NCHUNK * 4; ++p) z += zP[base + (size_t)p * 64];

  rZ[idx] = 1.0f / z;
}

// ---------------------------------------------------------------------------
// Kernel 3: output pass, ATOMIC-FREE. One block per (b, ib): full j-scan
// jb = 0..ib with a 2-deep K/V prefetch pipeline (even/odd register banks,
// all statically indexed). Each output row written exactly once -> plain
// coalesced stores, no memset needed. b = wg&7 keeps the XCD swizzle.
// ---------------------------------------------------------------------------
#define LOADKV(KR, VR, J0V) do { \
  _Pragma("unroll") \
  for (int jt = 0; jt < 4; ++jt) { \
    KR[jt][0] = ldfrag(Kb + (size_t)((J0V) + jt * 16 + lr) * 64 + lg * 8); \
    KR[jt][1] = ldfrag(Kb + (size_t)((J0V) + jt * 16 + lr) * 64 + 32 + lg * 8); \
  } \
  _Pragma("unroll") \
  for (int dt = 0; dt < 4; ++dt) { \
    VR[dt][0] = ldfrag(Vb + (size_t)(dt * 16 + lr) * S_N + (J0V) + lg * 8); \
    VR[dt][1] = ldfrag(Vb + (size_t)(dt * 16 + lr) * S_N + (J0V) + 32 + lg * 8); \
  } \
} while (0)

#define COMPUTE(KR, VR, J0V) do { \
  f32x4 s4[4]; \
  _Pragma("unroll") \
  for (int jt = 0; jt < 4; ++jt) { \
    f32x4 s = {0.f, 0.f, 0.f, 0.f}; \
    s = __builtin_amdgcn_mfma_f32_16x16x32_bf16(aq0, KR[jt][0], s, 0, 0, 0); \
    s = __builtin_amdgcn_mfma_f32_16x16x32_bf16(aq1, KR[jt][1], s, 0, 0, 0); \
    s4[jt] = s; \
  } \
  _Pragma("unroll") \
  for (int jt = 0; jt < 4; ++jt) { \
    const int jg = (J0V) + jt * 16 + lr; \
    const float rz = rZb[jg]; \
    _Pragma("unroll") \
    for (int r = 0; r < 4; ++r) { \
      const float pv = (jg <= ibase + r) ? __expf(s4[jt][r]) * rz : 0.f; \
      P_lds[w][lg * 4 + r][jt * 16 + lr] = (__bf16)pv; \
    } \
  } \
  const bf16x8 ap0 = ldfrag(&P_lds[w][lr][lg * 8]); \
  const bf16x8 ap1 = ldfrag(&P_lds[w][lr][32 + lg * 8]); \
  _Pragma("unroll") \
  for (int dt = 0; dt < 4; ++dt) { \
    o[dt] = __builtin_amdgcn_mfma_f32_16x16x32_bf16(ap0, VR[dt][0], o[dt], 0, 0, 0); \
    o[dt] = __builtin_amdgcn_mfma_f32_16x16x32_bf16(ap1, VR[dt][1], o[dt], 0, 0, 0); \
  } \
} while (0)

__global__ __launch_bounds__(256) void attn_out(
    const __bf16* __restrict__ Q, const __bf16* __restrict__ K,
    const __bf16* __restrict__ Vt, const float* __restrict__ rZ,
    float* __restrict__ out) {
  const int wg = blockIdx.x;                       // 256 blocks
  const int b  = wg & 7;                           // XCD swizzle
  const int ib = wg >> 3;                          // 0..31

  const int t = threadIdx.x;
  const int w = t >> 6, lane = t & 63, lr = lane & 15, lg = lane >> 4;
  const int i0 = ib * 64;

  __shared__ __align__(16) __bf16 P_lds[4][16][72];  // per-wave 16x64 (+pad 8)

  const __bf16* Qb = Q + (size_t)b * S_N * 64;
  const __bf16* Kb = K + (size_t)b * S_N * 64;
  const __bf16* Vb = Vt + (size_t)b * D_N * S_N;
  const float* rZb = rZ + (size_t)b * S_N;

  const int ri = i0 + w * 16 + lr;
  const bf16x8 aq0 = ldfrag(Qb + (size_t)ri * 64 + lg * 8);
  const bf16x8 aq1 = ldfrag(Qb + (size_t)ri * 64 + 32 + lg * 8);
  const int ibase = i0 + w * 16 + lg * 4;          // D-row base

  f32x4 o[4];
#pragma unroll
  for (int dt = 0; dt < 4; ++dt) o[dt] = {0.f, 0.f, 0.f, 0.f};

  bf16x8 kA[4][2], vA[4][2], kB[4][2], vB[4][2];

  LOADKV(kA, vA, 0);
  int jb = 0;
  while (true) {
    const bool hasB = (jb + 1 <= ib);
    if (hasB) LOADKV(kB, vB, (jb + 1) * 64);       // prefetch under A's chain
    COMPUTE(kA, vA, jb * 64);
    if (!hasB) break;
    const bool hasA2 = (jb + 2 <= ib);
    if (hasA2) LOADKV(kA, vA, (jb + 2) * 64);      // prefetch under B's chain
    COMPUTE(kB, vB, (jb + 1) * 64);
    if (!hasA2) break;
    jb += 2;
  }

  float* ob = out + (size_t)b * S_N * D_N;
#pragma unroll
  for (int dt = 0; dt < 4; ++dt)
#pragma unroll
    for (int r = 0; r < 4; ++r)
      ob[(size_t)(ibase + r) * D_N + dt * 16 + lr] = o[dt][r];
}

extern "C" void kernel_launch(void* const* d_in, const int* in_sizes, int n_in,
                              void* d_out, int out_size, void* d_ws, size_t ws_size,
                              hipStream_t stream) {
  (void)in_sizes; (void)n_in; (void)ws_size; (void)out_size;
  const float* x  = (const float*)d_in[0];
  const float* Wq = (const float*)d_in[1];
  const float* Wk = (const float*)d_in[2];
  const float* Wv = (const float*)d_in[3];
  float* out = (float*)d_out;

  __bf16* Qb = (__bf16*)d_ws;                         // [B*S][64] pre-scaled
  __bf16* Kb = Qb + (size_t)B_N * S_N * D_N;          // [B*S][64]
  __bf16* Vt = Kb + (size_t)B_N * S_N * D_N;          // [B][64][S] transposed
  float* rZ = (float*)(Vt + (size_t)B_N * S_N * D_N); // [B,S]
  float* zP = rZ + (size_t)B_N * S_N;                 // [B,32,NCHUNK,4,64]
  __bf16* Wt = (__bf16*)(zP + (size_t)B_N * 32 * NCHUNK * 4 * 64); // [3][64][384]

  w_prep<<<dim3(3 * 64 * C_N / 256), dim3(256), 0, stream>>>(Wq, Wk, Wv, Wt);
  qkv_mfma<<<dim3(B_N * S_N / 32), dim3(384), 0, stream>>>(x, Wt, Qb, Kb, Vt);
  col_part<<<dim3(32 * NCHUNK * B_N), dim3(256), 0, stream>>>(Qb, Kb, zP);
  col_reduce<<<dim3(B_N * S_N / 256), dim3(256), 0, stream>>>(zP, rZ);
  attn_out<<<dim3(32 * B_N), dim3(256), 0, stream>>>(Qb, Kb, Vt, rZ, out);
}